// Round 6
// baseline (259.052 us; speedup 1.0000x reference)
//
#include <hip/hip_runtime.h>
#include <hip/hip_bf16.h>

// CapsuleLayer dynamic routing. B=64, I=2048, D=16, J=32, K=16, routings=3.
// Proven by counters: inputs/outputs f32, ws >= 142.74 MB (single b-tile),
// W is L3-resident across replays, absmax margin 4.4x with bf16 u_hat.
//
// Round 6:
//  - produce: MFMA 16x16x32_bf16 (verified layouts). Block = one i, 4 waves =
//    4 b-tiles of 16. W_i staged to LDS as bf16 [j][cap_k][d] (48B k-stride).
//    A = W^T (m=cap_k, k=d), B = x (n=b, k=d), d in [16,32) zeroed.
//  - route: 4 groups x 8 i-rows with all loads hoisted (8 dwordx4 in flight).
//  - probe/b-tiling removed (hardcoded f32, BT=64).

#define B_ 64
#define I_ 2048
#define D_ 16
#define J_ 32
#define K_ 16
#define JK 512  // J_*K_

typedef __attribute__((ext_vector_type(8))) short short8;
typedef __attribute__((ext_vector_type(4))) float float4v;

__device__ __forceinline__ unsigned short f2bf(float f) {
    union { float f; unsigned int i; } v;
    v.f = f;
    const unsigned int x = v.i;
    return (unsigned short)((x + 0x7fffu + ((x >> 16) & 1u)) >> 16);  // RNE
}

// ---------------------------------------------------------------------------
// Producer (MFMA): grid I_ x 256 threads (4 waves). Wave w = b-tile w.
// LDS: W_i bf16 [j:32][cap_k:16][d:16], k-stride 48B (16B-aligned b128 reads,
// <=2-way bank aliasing). Per j: one mfma_f32_16x16x32_bf16:
//   A[m=cap_k=lane&15][k=d=quad*8+jj]   (quads 2,3 -> zero, d>=16)
//   B[k=d][n=b=lane&15]                 (x row, quads 2,3 -> zero)
//   C: row(m)=quad*4+reg, col(n)=lane&15  -> 4 consecutive cap_k -> 8B store.
// ---------------------------------------------------------------------------
__global__ __launch_bounds__(256)
void caps_produce(const float* __restrict__ x, const float* __restrict__ W,
                  unsigned short* __restrict__ uhat) {
    __shared__ unsigned short wlds[32 * 384];  // 32 j * 768B = 24 KB
    const int i = blockIdx.x;
    const int tid = threadIdx.x;

    // ---- stage W_i (32 KB f32) -> LDS bf16 [j][k][d] ----
    // thread t handles (j = t>>4 and t>>4 + 16, k = t&15): 16 d-strided loads.
    {
        const float* wbase = W + (size_t)i * (J_ * D_ * K_);
        const int k = tid & 15;
#pragma unroll
        for (int half = 0; half < 2; ++half) {
            const int j = (tid >> 4) + half * 16;
            const float* p = wbase + j * (D_ * K_) + k;
            float vals[16];
#pragma unroll
            for (int d = 0; d < 16; ++d) vals[d] = p[d * K_];
            unsigned int pk[8];
#pragma unroll
            for (int q = 0; q < 8; ++q)
                pk[q] = ((unsigned int)f2bf(vals[2 * q + 1]) << 16) |
                        f2bf(vals[2 * q]);
            uint4* dst = reinterpret_cast<uint4*>(wlds + j * 384 + k * 24);
            uint4 w0; w0.x = pk[0]; w0.y = pk[1]; w0.z = pk[2]; w0.w = pk[3];
            uint4 w1; w1.x = pk[4]; w1.y = pk[5]; w1.z = pk[6]; w1.w = pk[7];
            dst[0] = w0; dst[1] = w1;
        }
    }
    __syncthreads();

    const int lane = tid & 63;
    const int wv = tid >> 6;       // b-tile 0..3
    const int quad = lane >> 4;
    const int l15 = lane & 15;
    const int b = wv * 16 + l15;

    // B-frag: x[b, i, d=(quad&1)*8 .. +7], zero for quad>=2
    union { uint4 u; short8 s; } bf;
    {
        const float* xp = x + ((size_t)b * I_ + i) * D_ + (quad & 1) * 8;
        const float4 x0 = reinterpret_cast<const float4*>(xp)[0];
        const float4 x1 = reinterpret_cast<const float4*>(xp)[1];
        bf.u.x = ((unsigned int)f2bf(x0.y) << 16) | f2bf(x0.x);
        bf.u.y = ((unsigned int)f2bf(x0.w) << 16) | f2bf(x0.z);
        bf.u.z = ((unsigned int)f2bf(x1.y) << 16) | f2bf(x1.x);
        bf.u.w = ((unsigned int)f2bf(x1.w) << 16) | f2bf(x1.z);
        if (quad >= 2) { bf.u.x = 0; bf.u.y = 0; bf.u.z = 0; bf.u.w = 0; }
    }

    unsigned short* ubase = uhat + ((size_t)b * I_ + i) * JK + quad * 4;
    const unsigned short* abase = wlds + l15 * 24 + (quad & 1) * 8;

#pragma unroll 4
    for (int j = 0; j < 32; ++j) {
        union { uint4 u; short8 s; } af;
        af.u = *reinterpret_cast<const uint4*>(abase + j * 384);
        if (quad >= 2) { af.u.x = 0; af.u.y = 0; af.u.z = 0; af.u.w = 0; }
        float4v acc = {0.f, 0.f, 0.f, 0.f};
        acc = __builtin_amdgcn_mfma_f32_16x16x32_bf16(af.s, bf.s, acc, 0, 0, 0);
        uint2 pk;
        pk.x = ((unsigned int)f2bf(acc[1]) << 16) | f2bf(acc[0]);
        pk.y = ((unsigned int)f2bf(acc[3]) << 16) | f2bf(acc[2]);
        *reinterpret_cast<uint2*>(ubase + j * 16) = pk;
    }
}

// ---------------------------------------------------------------------------
// Routing pass: 4096 waves (4/block) = 64 b x 64 chunks (32 i each).
// lane: h = lane>>5 (i parity), j = lane&31. 4 groups of 8 i: all 8 dwordx4
// loads hoisted before compute (ILP). Softmax over j = 5 shfl within the
// 32-lane half (all its lanes share one i). Halves combined at the end.
// ---------------------------------------------------------------------------
template <bool R0>
__global__ __launch_bounds__(256)
void caps_route(const unsigned short* __restrict__ uhat,
                const float* __restrict__ vsum,
                float* __restrict__ spart) {
    const int lane = threadIdx.x & 63;
    const int wave = blockIdx.x * 4 + (threadIdx.x >> 6);
    const int bl = wave >> 6;     // b
    const int chunk = wave & 63;  // i-chunk
    const int i0 = chunk * 32;
    const int h = lane >> 5;
    const int j = lane & 31;

    float v[16];
    if (!R0) {
        const float4* vp =
            reinterpret_cast<const float4*>(vsum + bl * JK + j * 16);
        const float4 a0 = vp[0], a1 = vp[1], a2 = vp[2], a3 = vp[3];
        v[0] = a0.x; v[1] = a0.y; v[2] = a0.z; v[3] = a0.w;
        v[4] = a1.x; v[5] = a1.y; v[6] = a1.z; v[7] = a1.w;
        v[8] = a2.x; v[9] = a2.y; v[10] = a2.z; v[11] = a2.w;
        v[12] = a3.x; v[13] = a3.y; v[14] = a3.z; v[15] = a3.w;
    }

    float acc[16];
#pragma unroll
    for (int k = 0; k < 16; ++k) acc[k] = 0.f;

    const unsigned short* up = uhat + ((size_t)bl * I_ + i0 + h) * JK + j * 16;

    for (int g = 0; g < 4; ++g) {
        uint4 raw[4][2];
#pragma unroll
        for (int s = 0; s < 4; ++s) {
            const uint4* p = reinterpret_cast<const uint4*>(
                up + ((size_t)(g * 8 + 2 * s)) * JK);
            raw[s][0] = p[0];
            raw[s][1] = p[1];
        }
#pragma unroll
        for (int s = 0; s < 4; ++s) {
            float u[16];
            const unsigned int rr[8] = {raw[s][0].x, raw[s][0].y, raw[s][0].z,
                                        raw[s][0].w, raw[s][1].x, raw[s][1].y,
                                        raw[s][1].z, raw[s][1].w};
#pragma unroll
            for (int q = 0; q < 8; ++q) {
                union { unsigned int i; float f; } lo, hi;
                lo.i = rr[q] << 16;
                hi.i = rr[q] & 0xffff0000u;
                u[2 * q] = lo.f;
                u[2 * q + 1] = hi.f;
            }
            float c;
            if (R0) {
                c = 1.f;  // uniform coupling; 1/32 folded into squash
            } else {
                float p = 0.f;
#pragma unroll
                for (int k = 0; k < 16; ++k) p += u[k] * v[k];
                const float e = __expf(p);  // |p| bounded; f32-safe
                float S = e;  // sum over 32 j within the half
                S += __shfl_xor(S, 1, 64);
                S += __shfl_xor(S, 2, 64);
                S += __shfl_xor(S, 4, 64);
                S += __shfl_xor(S, 8, 64);
                S += __shfl_xor(S, 16, 64);
                c = e / (S + 1e-30f);
            }
#pragma unroll
            for (int k = 0; k < 16; ++k) acc[k] += c * u[k];
        }
    }

    // combine the two i-parity halves (same (b,j,k))
#pragma unroll
    for (int k = 0; k < 16; ++k) acc[k] += __shfl_xor(acc[k], 32, 64);

    if (h == 0) {
        float* sp = spart + ((size_t)chunk * B_ + bl) * JK + j * 16;
#pragma unroll
        for (int q = 0; q < 4; ++q) {
            float4 o;
            o.x = acc[q * 4 + 0]; o.y = acc[q * 4 + 1];
            o.z = acc[q * 4 + 2]; o.w = acc[q * 4 + 3];
            reinterpret_cast<float4*>(sp)[q] = o;
        }
    }
}

// ---------------------------------------------------------------------------
// Squash: grid = B_, 512 threads = (j = tid>>4, k = tid&15).
// MODE 0: s *= 1/32 (uniform c), vsum = v.  MODE 1: vsum += v.
// MODE 2: out = v (f32).
// ---------------------------------------------------------------------------
template <int MODE>
__global__ __launch_bounds__(512)
void caps_squash(const float* __restrict__ spart, float* __restrict__ vsum,
                 float* __restrict__ out) {
    const int bl = blockIdx.x;
    const int jk = threadIdx.x;
    float s = 0.f;
#pragma unroll 8
    for (int p = 0; p < 64; ++p)
        s += spart[((size_t)p * B_ + bl) * JK + jk];
    if (MODE == 0) s *= (1.f / 32.f);
    float q = s * s;  // reduce over k (16-lane groups, in-wave)
    q += __shfl_xor(q, 1, 64);
    q += __shfl_xor(q, 2, 64);
    q += __shfl_xor(q, 4, 64);
    q += __shfl_xor(q, 8, 64);
    const float scale = q / ((1.f + q) * sqrtf(q + 1e-7f));
    const float v = scale * s;
    if (MODE == 0)      vsum[bl * JK + jk] = v;
    else if (MODE == 1) vsum[bl * JK + jk] += v;
    else                out[(size_t)bl * JK + jk] = v;
}

// ---------------------------------------------------------------------------
extern "C" void kernel_launch(void* const* d_in, const int* in_sizes, int n_in,
                              void* d_out, int out_size, void* d_ws,
                              size_t ws_size, hipStream_t stream) {
    const float* x = (const float*)d_in[0];  // [B,I,D] f32
    const float* W = (const float*)d_in[1];  // [I,J,D,K] f32
    float* out = (float*)d_out;              // [B,J,K] f32

    char* ws = (char*)d_ws;
    unsigned short* uhat = (unsigned short*)ws;                   // 128 MiB
    float* spart = (float*)(ws + (size_t)B_ * I_ * JK * 2);       // 8 MiB
    float* vsum = spart + (size_t)64 * B_ * JK;                   // 128 KiB

    caps_produce<<<I_, 256, 0, stream>>>(x, W, uhat);

    caps_route<true><<<1024, 256, 0, stream>>>(uhat, vsum, spart);
    caps_squash<0><<<B_, 512, 0, stream>>>(spart, vsum, out);

    caps_route<false><<<1024, 256, 0, stream>>>(uhat, vsum, spart);
    caps_squash<1><<<B_, 512, 0, stream>>>(spart, vsum, out);

    caps_route<false><<<1024, 256, 0, stream>>>(uhat, vsum, spart);
    caps_squash<2><<<B_, 512, 0, stream>>>(spart, vsum, out);
}

// Round 7
// 254.128 us; speedup vs baseline: 1.0194x; 1.0194x over previous
//
#include <hip/hip_runtime.h>
#include <hip/hip_bf16.h>

// CapsuleLayer dynamic routing. B=64, I=2048, D=16, J=32, K=16, routings=3.
// Proven: f32 in/out, ws >= 142.74 MB, W/x HBM-read near-minimal (41 MB).
// Round 7:
//  - produce: MFMA + per-wave LDS transpose -> fully coalesced 1KB stores
//    (round-6 store scattered 8B/lane at 2MB stride = the bottleneck).
//  - route: lane=(k-half, j), one dwordx4 per row per lane (dense 1KB/instr),
//    k-halves merged with one shfl_xor(32); 8-deep row prefetch.

#define B_ 64
#define I_ 2048
#define D_ 16
#define J_ 32
#define K_ 16
#define JK 512  // J_*K_

typedef __attribute__((ext_vector_type(8))) short short8;
typedef __attribute__((ext_vector_type(4))) float float4v;

__device__ __forceinline__ unsigned short f2bf(float f) {
    union { float f; unsigned int i; } v;
    v.f = f;
    const unsigned int x = v.i;
    return (unsigned short)((x + 0x7fffu + ((x >> 16) & 1u)) >> 16);  // RNE
}

// ---------------------------------------------------------------------------
// Producer (MFMA): grid I_ x 256 threads (4 waves). Wave wv = b-tile of 16.
// LDS: W_i bf16 [j:32][cap_k:16][d:16] (k-stride 48B); zbuf = 16B zeros so
// quads 2,3 (d>=16) read zero A-frags without per-j cndmasks.
// Per j: mfma_f32_16x16x32_bf16, A=W^T (m=cap_k,k=d), B=x (n=b,k=d).
// C (row=cap_k quad*4+reg, col=b) packed to 8B -> per-wave LDS tile
// [b:16][jk-half:256 (+8 pad)] -> read back lane-contiguous -> 1KB dense
// global stores. Two j-halves to fit LDS (24K + 33K + zbuf < 64K).
// ---------------------------------------------------------------------------
__global__ __launch_bounds__(256)
void caps_produce(const float* __restrict__ x, const float* __restrict__ W,
                  unsigned short* __restrict__ uhat) {
    __shared__ unsigned short wlds[32 * 384];      // 24 KB
    __shared__ unsigned short zbuf[8];             // 16 B of zeros
    __shared__ unsigned short ctile[4][16 * 264];  // 33 KB (264 = 256+8 pad)
    const int i = blockIdx.x;
    const int tid = threadIdx.x;

    if (tid < 8) zbuf[tid] = 0;

    // ---- stage W_i (32 KB f32) -> LDS bf16 [j][k][d] ----
    {
        const float* wbase = W + (size_t)i * (J_ * D_ * K_);
        const int k = tid & 15;
#pragma unroll
        for (int half = 0; half < 2; ++half) {
            const int j = (tid >> 4) + half * 16;
            const float* p = wbase + j * (D_ * K_) + k;
            float vals[16];
#pragma unroll
            for (int d = 0; d < 16; ++d) vals[d] = p[d * K_];
            unsigned int pk[8];
#pragma unroll
            for (int q = 0; q < 8; ++q)
                pk[q] = ((unsigned int)f2bf(vals[2 * q + 1]) << 16) |
                        f2bf(vals[2 * q]);
            uint4* dst = reinterpret_cast<uint4*>(wlds + j * 384 + k * 24);
            uint4 w0; w0.x = pk[0]; w0.y = pk[1]; w0.z = pk[2]; w0.w = pk[3];
            uint4 w1; w1.x = pk[4]; w1.y = pk[5]; w1.z = pk[6]; w1.w = pk[7];
            dst[0] = w0; dst[1] = w1;
        }
    }
    __syncthreads();

    const int lane = tid & 63;
    const int wv = tid >> 6;   // b-tile
    const int quad = lane >> 4;
    const int l15 = lane & 15;
    const int b = wv * 16 + l15;

    // B-frag: x[b, i, (quad&1)*8 .. +7]; zero for quad>=2 (d>=16)
    union { uint4 u; short8 s; } bfrag;
    {
        const float* xp = x + ((size_t)b * I_ + i) * D_ + (quad & 1) * 8;
        const float4 x0 = reinterpret_cast<const float4*>(xp)[0];
        const float4 x1 = reinterpret_cast<const float4*>(xp)[1];
        bfrag.u.x = ((unsigned int)f2bf(x0.y) << 16) | f2bf(x0.x);
        bfrag.u.y = ((unsigned int)f2bf(x0.w) << 16) | f2bf(x0.z);
        bfrag.u.z = ((unsigned int)f2bf(x1.y) << 16) | f2bf(x1.x);
        bfrag.u.w = ((unsigned int)f2bf(x1.w) << 16) | f2bf(x1.z);
        if (quad >= 2) { bfrag.u.x = 0; bfrag.u.y = 0; bfrag.u.z = 0; bfrag.u.w = 0; }
    }

    // A-frag source: quads 2,3 read the 16B zero buffer (stride 0)
    const unsigned short* aptr =
        (quad >= 2) ? zbuf : (wlds + l15 * 24 + (quad & 1) * 8);
    const int astride = (quad >= 2) ? 0 : 384;
    unsigned short* ct = &ctile[wv][0];

    for (int jh = 0; jh < 2; ++jh) {
#pragma unroll
        for (int jj = 0; jj < 16; ++jj) {
            const int j = jh * 16 + jj;
            union { uint4 u; short8 s; } af;
            af.u = *reinterpret_cast<const uint4*>(aptr + (size_t)j * astride);
            float4v acc = {0.f, 0.f, 0.f, 0.f};
            acc = __builtin_amdgcn_mfma_f32_16x16x32_bf16(af.s, bfrag.s, acc,
                                                          0, 0, 0);
            uint2 pk;
            pk.x = ((unsigned int)f2bf(acc[1]) << 16) | f2bf(acc[0]);
            pk.y = ((unsigned int)f2bf(acc[3]) << 16) | f2bf(acc[2]);
            // [b=l15][jj*16 + quad*4 .. +3] within the wave's tile
            *reinterpret_cast<uint2*>(ct + l15 * 264 + jj * 16 + quad * 4) = pk;
        }
        // Same-wave readback (lgkmcnt ordering, no barrier): 1KB-dense stores.
#pragma unroll
        for (int r = 0; r < 8; ++r) {
            const int bsub = r * 2 + (lane >> 5);
            const int c32 = lane & 31;
            const uint4 val = *reinterpret_cast<const uint4*>(
                ct + bsub * 264 + c32 * 8);
            *reinterpret_cast<uint4*>(
                uhat + ((size_t)(wv * 16 + bsub) * I_ + i) * JK + jh * 256 +
                c32 * 8) = val;
        }
    }
}

// ---------------------------------------------------------------------------
// Routing pass: 4096 waves (4/block) = 64 b x 64 chunks (32 i each).
// lane: kh = lane>>5, j = lane&31 -> owns u_hat[b, i, j, kh*8..+7] (16B).
// One dwordx4 per row per lane; 64 lanes = 1KB dense per instr. Full dot via
// shfl_xor(32) (k-half merge); softmax denom = 5 shfl within 32-halves.
// 8-deep row prefetch per group.
// ---------------------------------------------------------------------------
template <bool R0>
__global__ __launch_bounds__(256)
void caps_route(const unsigned short* __restrict__ uhat,
                const float* __restrict__ vsum,
                float* __restrict__ spart) {
    const int lane = threadIdx.x & 63;
    const int wave = blockIdx.x * 4 + (threadIdx.x >> 6);
    const int bl = wave >> 6;     // b
    const int chunk = wave & 63;  // i-chunk
    const int i0 = chunk * 32;
    const int kh = lane >> 5;
    const int j = lane & 31;
    const int jk8 = j * 16 + kh * 8;  // element offset of this lane's 8 k's

    float v[8];
    if (!R0) {
        const float4* vp = reinterpret_cast<const float4*>(vsum + bl * JK + jk8);
        const float4 a0 = vp[0], a1 = vp[1];
        v[0] = a0.x; v[1] = a0.y; v[2] = a0.z; v[3] = a0.w;
        v[4] = a1.x; v[5] = a1.y; v[6] = a1.z; v[7] = a1.w;
    }

    float acc[8];
#pragma unroll
    for (int q = 0; q < 8; ++q) acc[q] = 0.f;

    const unsigned short* up = uhat + ((size_t)bl * I_ + i0) * JK + jk8;

    for (int g = 0; g < 4; ++g) {
        uint4 raw[8];
#pragma unroll
        for (int s = 0; s < 8; ++s)
            raw[s] = *reinterpret_cast<const uint4*>(
                up + (size_t)(g * 8 + s) * JK);
#pragma unroll
        for (int s = 0; s < 8; ++s) {
            float u[8];
            const unsigned int rr[4] = {raw[s].x, raw[s].y, raw[s].z, raw[s].w};
#pragma unroll
            for (int q = 0; q < 4; ++q) {
                union { unsigned int i; float f; } lo, hi;
                lo.i = rr[q] << 16;
                hi.i = rr[q] & 0xffff0000u;
                u[2 * q] = lo.f;
                u[2 * q + 1] = hi.f;
            }
            float c;
            if (R0) {
                c = 1.f;  // uniform coupling; 1/32 folded into squash
            } else {
                float p = 0.f;
#pragma unroll
                for (int q = 0; q < 8; ++q) p += u[q] * v[q];
                p += __shfl_xor(p, 32, 64);  // merge k-halves: full dot(i,j)
                const float e = __expf(p);   // |p| bounded; f32-safe
                float S = e;                 // sum over 32 j (within half)
                S += __shfl_xor(S, 1, 64);
                S += __shfl_xor(S, 2, 64);
                S += __shfl_xor(S, 4, 64);
                S += __shfl_xor(S, 8, 64);
                S += __shfl_xor(S, 16, 64);
                c = e / S;
            }
#pragma unroll
            for (int q = 0; q < 8; ++q) acc[q] += c * u[q];
        }
    }

    float* sp = spart + ((size_t)chunk * B_ + bl) * JK + jk8;
    float4 o0, o1;
    o0.x = acc[0]; o0.y = acc[1]; o0.z = acc[2]; o0.w = acc[3];
    o1.x = acc[4]; o1.y = acc[5]; o1.z = acc[6]; o1.w = acc[7];
    reinterpret_cast<float4*>(sp)[0] = o0;
    reinterpret_cast<float4*>(sp)[1] = o1;
}

// ---------------------------------------------------------------------------
// Squash: grid = B_, 512 threads = (j = tid>>4, k = tid&15).
// MODE 0: s *= 1/32 (uniform c), vsum = v.  MODE 1: vsum += v.
// MODE 2: out = v (f32).
// ---------------------------------------------------------------------------
template <int MODE>
__global__ __launch_bounds__(512)
void caps_squash(const float* __restrict__ spart, float* __restrict__ vsum,
                 float* __restrict__ out) {
    const int bl = blockIdx.x;
    const int jk = threadIdx.x;
    float s = 0.f;
#pragma unroll 8
    for (int p = 0; p < 64; ++p)
        s += spart[((size_t)p * B_ + bl) * JK + jk];
    if (MODE == 0) s *= (1.f / 32.f);
    float q = s * s;  // reduce over k (16-lane groups, in-wave)
    q += __shfl_xor(q, 1, 64);
    q += __shfl_xor(q, 2, 64);
    q += __shfl_xor(q, 4, 64);
    q += __shfl_xor(q, 8, 64);
    const float scale = q / ((1.f + q) * sqrtf(q + 1e-7f));
    const float v = scale * s;
    if (MODE == 0)      vsum[bl * JK + jk] = v;
    else if (MODE == 1) vsum[bl * JK + jk] += v;
    else                out[(size_t)bl * JK + jk] = v;
}

// ---------------------------------------------------------------------------
extern "C" void kernel_launch(void* const* d_in, const int* in_sizes, int n_in,
                              void* d_out, int out_size, void* d_ws,
                              size_t ws_size, hipStream_t stream) {
    const float* x = (const float*)d_in[0];  // [B,I,D] f32
    const float* W = (const float*)d_in[1];  // [I,J,D,K] f32
    float* out = (float*)d_out;              // [B,J,K] f32

    char* ws = (char*)d_ws;
    unsigned short* uhat = (unsigned short*)ws;                // 128 MiB
    float* spart = (float*)(ws + (size_t)B_ * I_ * JK * 2);    // 8 MiB
    float* vsum = spart + (size_t)64 * B_ * JK;                // 128 KiB

    caps_produce<<<I_, 256, 0, stream>>>(x, W, uhat);

    caps_route<true><<<1024, 256, 0, stream>>>(uhat, vsum, spart);
    caps_squash<0><<<B_, 512, 0, stream>>>(spart, vsum, out);

    caps_route<false><<<1024, 256, 0, stream>>>(uhat, vsum, spart);
    caps_squash<1><<<B_, 512, 0, stream>>>(spart, vsum, out);

    caps_route<false><<<1024, 256, 0, stream>>>(uhat, vsum, spart);
    caps_squash<2><<<B_, 512, 0, stream>>>(spart, vsum, out);
}